// Round 6
// baseline (52.983 us; speedup 1.0000x reference)
//
#include <hip/hip_runtime.h>
#include <hip/hip_fp16.h>
#include <math.h>

#define Jn 161
#define Vn 131072
#define Kn 8
#define Bn 8
#define Pn 1127
#define NLOC 960   // P - 6 - J
#define MATU (Bn*Jn*6)    // packed-f16 matrices, in uints (2 halves each)
#define BPB 2             // batches per skin block
#define SMU (BPB*Jn*6)    // staged uints per skin block (1932 = 7.7 KB)
#define RPB 16            // GEMV rows per block
#define NGEMV ((Pn + RPB - 1) / RPB)   // 71
#define NPARB ((Jn + 3) / 4)           // 41 parent blocks (4 joints each)

struct Q  { float x, y, z, w; };
struct F3 { float x, y, z; };

__device__ __forceinline__ F3 cross3(F3 a, F3 b) {
    return F3{ a.y*b.z - a.z*b.y, a.z*b.x - a.x*b.z, a.x*b.y - a.y*b.x };
}
__device__ __forceinline__ Q qmul(Q a, Q b) {
    return Q{ a.w*b.x + a.x*b.w + a.y*b.z - a.z*b.y,
              a.w*b.y - a.x*b.z + a.y*b.w + a.z*b.x,
              a.w*b.z + a.x*b.y - a.y*b.x + a.z*b.w,
              a.w*b.w - a.x*b.x - a.y*b.y - a.z*b.z };
}
__device__ __forceinline__ F3 qrot(Q q, F3 v) {
    F3 qv{ q.x, q.y, q.z };
    F3 t = cross3(qv, v);
    t.x *= 2.f; t.y *= 2.f; t.z *= 2.f;
    F3 c = cross3(qv, t);
    return F3{ v.x + q.w*t.x + c.x, v.y + q.w*t.y + c.y, v.z + q.w*t.z + c.z };
}
__device__ __forceinline__ Q qfromxyz(float ex, float ey, float ez) {
    float sx, cx, sy, cy, sz, cz;
    __sincosf(0.5f*ex, &sx, &cx);
    __sincosf(0.5f*ey, &sy, &cy);
    __sincosf(0.5f*ez, &sz, &cz);
    return Q{ sx*cy*cz + cx*sy*sz,
              cx*sy*cz - sx*cy*sz,
              cx*cy*sz + sx*sy*cz,
              cx*cy*cz - sx*sy*sz };
}

__device__ __forceinline__ unsigned packh2(float a, float b) {
    unsigned lo = (unsigned)__half_as_ushort(__float2half_rn(a));
    unsigned hi = (unsigned)__half_as_ushort(__float2half_rn(b));
    return lo | (hi << 16);
}
__device__ __forceinline__ float2 unpackh2(unsigned u) {
    float2 r;
    r.x = __half2float(__ushort_as_half((unsigned short)(u & 0xFFFFu)));
    r.y = __half2float(__ushort_as_half((unsigned short)(u >> 16)));
    return r;
}

// local transform of joint i for batch b, computed from params on the fly
__device__ __forceinline__ void local_of(
    const float* __restrict__ params, const float* __restrict__ joff,
    const float* __restrict__ jrot, int b, int i,
    F3& lt, Q& lr, float& ls)
{
    const float* jp = params + b*Pn + i*7;
    Q fx = qfromxyz(jp[3], jp[4], jp[5]);
    Q jr{ jrot[i*4+0], jrot[i*4+1], jrot[i*4+2], jrot[i*4+3] };
    lr = qmul(jr, fx);
    lt = F3{ jp[0] + joff[i*3+0], jp[1] + joff[i*3+1], jp[2] + joff[i*3+2] };
    ls = exp2f(jp[6]);
}

// ---------------------------------------------------------------------------
// Kernel A: blocks 0..NGEMV-1: GEMV rows (pose staged in LDS, wave per row);
// blocks NGEMV..NGEMV+NPARB-1: parents recovery (wave per joint).
// ---------------------------------------------------------------------------
__global__ __launch_bounds__(256) void k_front(
    const float* __restrict__ gp, const float* __restrict__ lp,
    const float* __restrict__ sc, const float* __restrict__ T,
    const float* __restrict__ toff, const float* __restrict__ joff,
    const float* __restrict__ jrot, const float* __restrict__ bind,
    float* __restrict__ params, int* __restrict__ parents)
{
    const int blk  = blockIdx.x;
    const int tid  = threadIdx.x;
    const int wid  = tid >> 6;
    const int lane = tid & 63;

    if (blk < NGEMV) {
        // ---- GEMV: rows r0..r0+RPB-1 ----
        __shared__ float poseS[Bn*Pn];   // 36 KB
        for (int t = tid; t < Bn*Pn; t += 256) {
            const int b = t / Pn;
            const int q = t - b*Pn;
            float v;
            if (q < 6)            v = gp[b*6 + q];
            else if (q < 6+NLOC)  v = lp[b*NLOC + (q-6)];
            else                  v = sc[b*Jn + (q-6-NLOC)];
            poseS[t] = v;
        }
        __syncthreads();

        const int r0 = blk * RPB;
        for (int rr = 0; rr < RPB/4; ++rr) {
            const int row = r0 + wid + 4*rr;
            if (row >= Pn) break;
            const float* trow = T + (size_t)row * Pn;
            float acc[Bn];
            #pragma unroll
            for (int b = 0; b < Bn; ++b) acc[b] = 0.f;
            for (int q = lane; q < Pn; q += 64) {
                float tv = trow[q];
                #pragma unroll
                for (int b = 0; b < Bn; ++b)
                    acc[b] = fmaf(tv, poseS[b*Pn + q], acc[b]);
            }
            #pragma unroll
            for (int b = 0; b < Bn; ++b)
                #pragma unroll
                for (int o = 32; o > 0; o >>= 1)
                    acc[b] += __shfl_xor(acc[b], o, 64);
            if (lane == 0) {
                float off = toff[row];
                #pragma unroll
                for (int b = 0; b < Bn; ++b)
                    params[b*Pn + row] = acc[b] + off;
            }
        }
        return;
    }

    // ---- parents: wave per joint ----
    const int i = (blk - NGEMV) * 4 + wid;
    if (i >= Jn) return;
    if (i == 0) { if (lane == 0) parents[0] = -1; return; }

    Q fx = qfromxyz(toff[i*7+3], toff[i*7+4], toff[i*7+5]);
    Q jr{ jrot[i*4+0], jrot[i*4+1], jrot[i*4+2], jrot[i*4+3] };
    Q lr = qmul(jr, fx);
    const float l0 = toff[i*7+0] + joff[i*3+0];
    const float l1 = toff[i*7+1] + joff[i*3+1];
    const float l2 = toff[i*7+2] + joff[i*3+2];
    const float lsc = exp2f(toff[i*7+6]);

    float bi[8];
    #pragma unroll
    for (int c = 0; c < 8; ++c) bi[c] = bind[i*8+c];

    unsigned best = 0xFFFFFFFFu;
    for (int p = lane; p < i; p += 64) {
        const float* bp = bind + p*8;
        Q  pr{ bp[3], bp[4], bp[5], bp[6] };
        float ps = bp[7];
        Q  gr = qmul(pr, lr);
        F3 gt = qrot(pr, F3{ l0*ps, l1*ps, l2*ps });
        gt.x += bp[0]; gt.y += bp[1]; gt.z += bp[2];
        float gs = ps * lsc;
        float err = 0.f, d;
        d = gr.x - bi[3]; err += d*d;
        d = gr.y - bi[4]; err += d*d;
        d = gr.z - bi[5]; err += d*d;
        d = gr.w - bi[6]; err += d*d;
        d = gt.x - bi[0]; err += d*d;
        d = gt.y - bi[1]; err += d*d;
        d = gt.z - bi[2]; err += d*d;
        d = gs   - bi[7]; err += d*d;
        unsigned pk = (__float_as_uint(err) & 0xFFFFFF00u) | (unsigned)p;
        best = best < pk ? best : pk;
    }
    #pragma unroll
    for (int o = 32; o > 0; o >>= 1) {
        unsigned other = __shfl_xor(best, o, 64);
        best = best < other ? best : other;
    }
    if (lane == 0) parents[i] = (int)(best & 0xFFu);
}

// ---------------------------------------------------------------------------
// Kernel B: flat FK — thread = one (batch, joint) unit. No LDS, no barriers;
// walks ancestors reading params/jrot/joff from L2, recomputing locals on
// the fly. 1288 units over 21 x 64-thread blocks (full-GPU spread).
// ---------------------------------------------------------------------------
__global__ __launch_bounds__(64) void k_fk(
    const float* __restrict__ params, const float* __restrict__ joff,
    const float* __restrict__ jrot,   const float* __restrict__ bind,
    const int* __restrict__ parents,  unsigned* __restrict__ mat16)
{
    const int t = blockIdx.x * 64 + threadIdx.x;
    if (t >= Bn*Jn) return;
    const int b = t / Jn;
    const int i = t - b*Jn;

    F3 at; Q ar; float as;
    local_of(params, joff, jrot, b, i, at, ar, as);

    int j = parents[i];
    while (j >= 0) {
        F3 lt; Q lq; float ls;
        local_of(params, joff, jrot, b, j, lt, lq, ls);
        F3 nt = qrot(lq, F3{ at.x*ls, at.y*ls, at.z*ls });
        at = F3{ nt.x + lt.x, nt.y + lt.y, nt.z + lt.z };
        ar = qmul(lq, ar);
        as = ls * as;
        j = parents[j];
    }

    const float* bv = bind + i*8;
    Q  br{ -bv[3], -bv[4], -bv[5], bv[6] };
    float bs = 1.f / bv[7];
    F3 btv = qrot(br, F3{ -bv[0], -bv[1], -bv[2] });
    btv.x *= bs; btv.y *= bs; btv.z *= bs;

    Q  tr = qmul(ar, br);
    float ts = as * bs;
    F3 tt = qrot(ar, F3{ btv.x*as, btv.y*as, btv.z*as });
    tt.x += at.x; tt.y += at.y; tt.z += at.z;

    float x = tr.x, y = tr.y, z = tr.z, w = tr.w;
    float twx = 2.f*x*w, twy = 2.f*y*w, twz = 2.f*z*w;
    float txx = 2.f*x*x, txy = 2.f*y*x, txz = 2.f*z*x;
    float tyy = 2.f*y*y, tyz = 2.f*z*y, tzz = 2.f*z*z;

    float m0  = (1.f - (tyy + tzz)) * ts;
    float m1  = (txy - twz) * ts;
    float m2  = (txz + twy) * ts;
    float m3  = tt.x;
    float m4  = (txy + twz) * ts;
    float m5  = (1.f - (txx + tzz)) * ts;
    float m6  = (tyz - twx) * ts;
    float m7  = tt.y;
    float m8  = (txz - twy) * ts;
    float m9  = (tyz + twx) * ts;
    float m10 = (1.f - (txx + tyy)) * ts;
    float m11 = tt.z;

    unsigned* o = mat16 + (size_t)t * 6;
    o[0] = packh2(m0,  m1);
    o[1] = packh2(m2,  m3);
    o[2] = packh2(m4,  m5);
    o[3] = packh2(m6,  m7);
    o[4] = packh2(m8,  m9);
    o[5] = packh2(m10, m11);
}

// ---------------------------------------------------------------------------
// Kernel C: skinning (unchanged from R5 — control). Thread = 1 vertex x 2
// batches; 2048 blocks; 7.7 KB LDS.
// ---------------------------------------------------------------------------
__global__ __launch_bounds__(256) void k_skin(
    const unsigned* __restrict__ mat16, const float* __restrict__ wts,
    const float* __restrict__ verts, const int* __restrict__ idx,
    float* __restrict__ out)
{
    __shared__ unsigned sm[SMU];      // 1932 uints = 7.7 KB
    const int tid = threadIdx.x;
    const int pb  = blockIdx.x & 3;          // batch pair 0..3
    const int vbk = blockIdx.x >> 2;         // vertex block 0..511
    const int b0  = pb * BPB;

    {
        const uint4* g4 = (const uint4*)(mat16 + (size_t)b0 * Jn * 6);
        uint4* s4 = (uint4*)sm;
        #pragma unroll
        for (int t = tid; t < SMU/4; t += 256) s4[t] = g4[t];
    }
    __syncthreads();

    const int v = vbk * 256 + tid;

    const int4*   ip = (const int4*)(idx) + v*2;
    const float4* wp = (const float4*)(wts) + v*2;
    int4   i0 = ip[0], i1 = ip[1];
    float4 w0 = wp[0], w1 = wp[1];

    const float vx = verts[v*3+0], vy = verts[v*3+1], vz = verts[v*3+2];

    int   jj[Kn] = { i0.x, i0.y, i0.z, i0.w, i1.x, i1.y, i1.z, i1.w };
    float ww[Kn] = { w0.x, w0.y, w0.z, w0.w, w1.x, w1.y, w1.z, w1.w };

    #pragma unroll
    for (int b = 0; b < BPB; ++b) {
        float a0 = 0.f, a1 = 0.f, a2 = 0.f;
        #pragma unroll
        for (int k = 0; k < Kn; ++k) {
            const int base = (b*Jn + jj[k]) * 6;
            uint2 q0 = *(const uint2*)&sm[base];
            uint2 q1 = *(const uint2*)&sm[base+2];
            uint2 q2 = *(const uint2*)&sm[base+4];
            float2 ma = unpackh2(q0.x), mb = unpackh2(q0.y);
            float2 mc = unpackh2(q1.x), md = unpackh2(q1.y);
            float2 me = unpackh2(q2.x), mf = unpackh2(q2.y);
            float wk = ww[k];
            a0 = fmaf(wk, fmaf(ma.x, vx, fmaf(ma.y, vy, fmaf(mb.x, vz, mb.y))), a0);
            a1 = fmaf(wk, fmaf(mc.x, vx, fmaf(mc.y, vy, fmaf(md.x, vz, md.y))), a1);
            a2 = fmaf(wk, fmaf(me.x, vx, fmaf(me.y, vy, fmaf(mf.x, vz, mf.y))), a2);
        }
        float* o = out + ((size_t)(b0 + b)*Vn + v) * 3;
        o[0] = a0; o[1] = a1; o[2] = a2;
    }
}

// ---------------------------------------------------------------------------
extern "C" void kernel_launch(void* const* d_in, const int* in_sizes, int n_in,
                              void* d_out, int out_size, void* d_ws, size_t ws_size,
                              hipStream_t stream)
{
    (void)in_sizes; (void)n_in; (void)out_size; (void)ws_size;

    const float* gp    = (const float*)d_in[0];   // global_pose   [8,6]
    const float* lp    = (const float*)d_in[1];   // local_pose    [8,960]
    const float* sc    = (const float*)d_in[2];   // scale         [8,161]
    const float* T     = (const float*)d_in[3];   // transform     [1127,1127]
    const float* toff  = (const float*)d_in[4];   // transform_offsets [1127]
    const float* joff  = (const float*)d_in[5];   // joint_offset  [161,3]
    const float* jrot  = (const float*)d_in[6];   // joint_rotation[161,4]
    const float* bind  = (const float*)d_in[7];   // bind_state    [1,161,8]
    const float* wts   = (const float*)d_in[8];   // skin_weights  [131072,8]
    const float* verts = (const float*)d_in[9];   // mesh_vertices [131072,3]
    const int*   idx   = (const int*)d_in[10];    // skin_indices  [131072,8]
    float* out = (float*)d_out;

    char* ws = (char*)d_ws;
    float*    params  = (float*)ws;                 // 8*1127 f32 @ 0     (36 KB)
    int*      parents = (int*)(ws + 40960);         // 161 ints   @ 40 KB
    unsigned* mat16   = (unsigned*)(ws + 45056);    // 7728 uints @ 44 KB (31 KB)

    k_front<<<NGEMV + NPARB, 256, 0, stream>>>(gp, lp, sc, T, toff, joff, jrot, bind, params, parents);
    k_fk   <<<(Bn*Jn + 63)/64, 64, 0, stream>>>(params, joff, jrot, bind, parents, mat16);
    k_skin <<<(Vn/256)*(Bn/BPB), 256, 0, stream>>>(mat16, wts, verts, idx, out);
}

// Round 7
// 29.984 us; speedup vs baseline: 1.7670x; 1.7670x over previous
//
#include <hip/hip_runtime.h>
#include <hip/hip_fp16.h>
#include <math.h>

#define Jn 161
#define Vn 131072
#define Kn 8
#define Bn 8
#define Pn 1127
#define NLOC 960   // P - 6 - J
#define BPB 2             // batches per skin block
#define SMU (BPB*Jn*6)    // staged uints per skin block (1932 = 7.7 KB)
#define NPARB ((Jn + 3) / 4)   // 41 parent blocks (4 joints each, wave per joint)

struct Q  { float x, y, z, w; };
struct F3 { float x, y, z; };

__device__ __forceinline__ F3 cross3(F3 a, F3 b) {
    return F3{ a.y*b.z - a.z*b.y, a.z*b.x - a.x*b.z, a.x*b.y - a.y*b.x };
}
__device__ __forceinline__ Q qmul(Q a, Q b) {
    return Q{ a.w*b.x + a.x*b.w + a.y*b.z - a.z*b.y,
              a.w*b.y - a.x*b.z + a.y*b.w + a.z*b.x,
              a.w*b.z + a.x*b.y - a.y*b.x + a.z*b.w,
              a.w*b.w - a.x*b.x - a.y*b.y - a.z*b.z };
}
__device__ __forceinline__ F3 qrot(Q q, F3 v) {
    F3 qv{ q.x, q.y, q.z };
    F3 t = cross3(qv, v);
    t.x *= 2.f; t.y *= 2.f; t.z *= 2.f;
    F3 c = cross3(qv, t);
    return F3{ v.x + q.w*t.x + c.x, v.y + q.w*t.y + c.y, v.z + q.w*t.z + c.z };
}
__device__ __forceinline__ Q qfromxyz(float ex, float ey, float ez) {
    float sx, cx, sy, cy, sz, cz;
    __sincosf(0.5f*ex, &sx, &cx);
    __sincosf(0.5f*ey, &sy, &cy);
    __sincosf(0.5f*ez, &sz, &cz);
    return Q{ sx*cy*cz + cx*sy*sz,
              cx*sy*cz - sx*cy*sz,
              cx*cy*sz + sx*sy*cz,
              cx*cy*cz - sx*sy*sz };
}

__device__ __forceinline__ unsigned packh2(float a, float b) {
    unsigned lo = (unsigned)__half_as_ushort(__float2half_rn(a));
    unsigned hi = (unsigned)__half_as_ushort(__float2half_rn(b));
    return lo | (hi << 16);
}
__device__ __forceinline__ float2 unpackh2(unsigned u) {
    float2 r;
    r.x = __half2float(__ushort_as_half((unsigned short)(u & 0xFFFFu)));
    r.y = __half2float(__ushort_as_half((unsigned short)(u >> 16)));
    return r;
}

// local transform of joint i for batch b, computed from params on the fly
__device__ __forceinline__ void local_of(
    const float* __restrict__ params, const float* __restrict__ joff,
    const float* __restrict__ jrot, int b, int i,
    F3& lt, Q& lr, float& ls)
{
    const float* jp = params + b*Pn + i*7;
    Q fx = qfromxyz(jp[3], jp[4], jp[5]);
    Q jr{ jrot[i*4+0], jrot[i*4+1], jrot[i*4+2], jrot[i*4+3] };
    lr = qmul(jr, fx);
    lt = F3{ jp[0] + joff[i*3+0], jp[1] + joff[i*3+1], jp[2] + joff[i*3+2] };
    ls = exp2f(jp[6]);
}

// ---------------------------------------------------------------------------
// Kernel A: blocks 0..Pn-1: one GEMV row per 256-thread block, loads unrolled
// and hoisted (5 T-loads in flight), butterfly + LDS cross-wave reduce.
// Blocks Pn..Pn+NPARB-1: parents recovery (wave per joint).
// ---------------------------------------------------------------------------
__global__ __launch_bounds__(256) void k_front(
    const float* __restrict__ gp, const float* __restrict__ lp,
    const float* __restrict__ sc, const float* __restrict__ T,
    const float* __restrict__ toff, const float* __restrict__ joff,
    const float* __restrict__ jrot, const float* __restrict__ bind,
    float* __restrict__ params, int* __restrict__ parents)
{
    __shared__ float sPart[4*Bn];
    const int blk  = blockIdx.x;
    const int tid  = threadIdx.x;
    const int wid  = tid >> 6;
    const int lane = tid & 63;

    if (blk < Pn) {
        const int row = blk;
        const float* trow = T + (size_t)row * Pn;

        // hoisted, unrolled loads: q = tid + k*256, k = 0..4
        float tv[5];
        #pragma unroll
        for (int k = 0; k < 5; ++k) {
            const int q = tid + k*256;
            tv[k] = (q < Pn) ? trow[q] : 0.f;
        }
        float pv[5][Bn];
        #pragma unroll
        for (int k = 0; k < 5; ++k) {
            const int q = tid + k*256;
            #pragma unroll
            for (int b = 0; b < Bn; ++b) {
                float v = 0.f;
                if (q < 6)             v = gp[b*6 + q];
                else if (q < 6+NLOC)   v = lp[b*NLOC + (q-6)];
                else if (q < Pn)       v = sc[b*Jn + (q-6-NLOC)];
                pv[k][b] = v;
            }
        }

        float acc[Bn];
        #pragma unroll
        for (int b = 0; b < Bn; ++b) acc[b] = 0.f;
        #pragma unroll
        for (int k = 0; k < 5; ++k)
            #pragma unroll
            for (int b = 0; b < Bn; ++b)
                acc[b] = fmaf(tv[k], pv[k][b], acc[b]);

        #pragma unroll
        for (int b = 0; b < Bn; ++b)
            #pragma unroll
            for (int o = 32; o > 0; o >>= 1)
                acc[b] += __shfl_xor(acc[b], o, 64);

        if (lane == 0) {
            #pragma unroll
            for (int b = 0; b < Bn; ++b) sPart[wid*Bn + b] = acc[b];
        }
        __syncthreads();
        if (tid < Bn) {
            float s = sPart[tid] + sPart[Bn+tid] + sPart[2*Bn+tid] + sPart[3*Bn+tid];
            params[tid*Pn + row] = s + toff[row];
        }
        return;
    }

    // ---- parents: wave per joint ----
    const int i = (blk - Pn) * 4 + wid;
    if (i >= Jn) return;
    if (i == 0) { if (lane == 0) parents[0] = -1; return; }

    Q fx = qfromxyz(toff[i*7+3], toff[i*7+4], toff[i*7+5]);
    Q jr{ jrot[i*4+0], jrot[i*4+1], jrot[i*4+2], jrot[i*4+3] };
    Q lr = qmul(jr, fx);
    const float l0 = toff[i*7+0] + joff[i*3+0];
    const float l1 = toff[i*7+1] + joff[i*3+1];
    const float l2 = toff[i*7+2] + joff[i*3+2];
    const float lsc = exp2f(toff[i*7+6]);

    float bi[8];
    #pragma unroll
    for (int c = 0; c < 8; ++c) bi[c] = bind[i*8+c];

    unsigned best = 0xFFFFFFFFu;
    for (int p = lane; p < i; p += 64) {
        const float* bp = bind + p*8;
        Q  pr{ bp[3], bp[4], bp[5], bp[6] };
        float ps = bp[7];
        Q  gr = qmul(pr, lr);
        F3 gt = qrot(pr, F3{ l0*ps, l1*ps, l2*ps });
        gt.x += bp[0]; gt.y += bp[1]; gt.z += bp[2];
        float gs = ps * lsc;
        float err = 0.f, d;
        d = gr.x - bi[3]; err += d*d;
        d = gr.y - bi[4]; err += d*d;
        d = gr.z - bi[5]; err += d*d;
        d = gr.w - bi[6]; err += d*d;
        d = gt.x - bi[0]; err += d*d;
        d = gt.y - bi[1]; err += d*d;
        d = gt.z - bi[2]; err += d*d;
        d = gs   - bi[7]; err += d*d;
        unsigned pk = (__float_as_uint(err) & 0xFFFFFF00u) | (unsigned)p;
        best = best < pk ? best : pk;
    }
    #pragma unroll
    for (int o = 32; o > 0; o >>= 1) {
        unsigned other = __shfl_xor(best, o, 64);
        best = best < other ? best : other;
    }
    if (lane == 0) parents[i] = (int)(best & 0xFFu);
}

// ---------------------------------------------------------------------------
// Kernel B: flat FK — thread = one (batch, joint) unit. No LDS, no barriers.
// ---------------------------------------------------------------------------
__global__ __launch_bounds__(64) void k_fk(
    const float* __restrict__ params, const float* __restrict__ joff,
    const float* __restrict__ jrot,   const float* __restrict__ bind,
    const int* __restrict__ parents,  unsigned* __restrict__ mat16)
{
    const int t = blockIdx.x * 64 + threadIdx.x;
    if (t >= Bn*Jn) return;
    const int b = t / Jn;
    const int i = t - b*Jn;

    F3 at; Q ar; float as;
    local_of(params, joff, jrot, b, i, at, ar, as);

    int j = parents[i];
    while (j >= 0) {
        F3 lt; Q lq; float ls;
        local_of(params, joff, jrot, b, j, lt, lq, ls);
        F3 nt = qrot(lq, F3{ at.x*ls, at.y*ls, at.z*ls });
        at = F3{ nt.x + lt.x, nt.y + lt.y, nt.z + lt.z };
        ar = qmul(lq, ar);
        as = ls * as;
        j = parents[j];
    }

    const float* bv = bind + i*8;
    Q  br{ -bv[3], -bv[4], -bv[5], bv[6] };
    float bs = 1.f / bv[7];
    F3 btv = qrot(br, F3{ -bv[0], -bv[1], -bv[2] });
    btv.x *= bs; btv.y *= bs; btv.z *= bs;

    Q  tr = qmul(ar, br);
    float ts = as * bs;
    F3 tt = qrot(ar, F3{ btv.x*as, btv.y*as, btv.z*as });
    tt.x += at.x; tt.y += at.y; tt.z += at.z;

    float x = tr.x, y = tr.y, z = tr.z, w = tr.w;
    float twx = 2.f*x*w, twy = 2.f*y*w, twz = 2.f*z*w;
    float txx = 2.f*x*x, txy = 2.f*y*x, txz = 2.f*z*x;
    float tyy = 2.f*y*y, tyz = 2.f*z*y, tzz = 2.f*z*z;

    float m0  = (1.f - (tyy + tzz)) * ts;
    float m1  = (txy - twz) * ts;
    float m2  = (txz + twy) * ts;
    float m3  = tt.x;
    float m4  = (txy + twz) * ts;
    float m5  = (1.f - (txx + tzz)) * ts;
    float m6  = (tyz - twx) * ts;
    float m7  = tt.y;
    float m8  = (txz - twy) * ts;
    float m9  = (tyz + twx) * ts;
    float m10 = (1.f - (txx + tyy)) * ts;
    float m11 = tt.z;

    unsigned* o = mat16 + (size_t)t * 6;
    o[0] = packh2(m0,  m1);
    o[1] = packh2(m2,  m3);
    o[2] = packh2(m4,  m5);
    o[3] = packh2(m6,  m7);
    o[4] = packh2(m8,  m9);
    o[5] = packh2(m10, m11);
}

// ---------------------------------------------------------------------------
// Kernel C: skinning (unchanged — control). Thread = 1 vertex x 2 batches;
// 2048 blocks; 7.7 KB LDS.
// ---------------------------------------------------------------------------
__global__ __launch_bounds__(256) void k_skin(
    const unsigned* __restrict__ mat16, const float* __restrict__ wts,
    const float* __restrict__ verts, const int* __restrict__ idx,
    float* __restrict__ out)
{
    __shared__ unsigned sm[SMU];      // 1932 uints = 7.7 KB
    const int tid = threadIdx.x;
    const int pb  = blockIdx.x & 3;          // batch pair 0..3
    const int vbk = blockIdx.x >> 2;         // vertex block 0..511
    const int b0  = pb * BPB;

    {
        const uint4* g4 = (const uint4*)(mat16 + (size_t)b0 * Jn * 6);
        uint4* s4 = (uint4*)sm;
        #pragma unroll
        for (int t = tid; t < SMU/4; t += 256) s4[t] = g4[t];
    }
    __syncthreads();

    const int v = vbk * 256 + tid;

    const int4*   ip = (const int4*)(idx) + v*2;
    const float4* wp = (const float4*)(wts) + v*2;
    int4   i0 = ip[0], i1 = ip[1];
    float4 w0 = wp[0], w1 = wp[1];

    const float vx = verts[v*3+0], vy = verts[v*3+1], vz = verts[v*3+2];

    int   jj[Kn] = { i0.x, i0.y, i0.z, i0.w, i1.x, i1.y, i1.z, i1.w };
    float ww[Kn] = { w0.x, w0.y, w0.z, w0.w, w1.x, w1.y, w1.z, w1.w };

    #pragma unroll
    for (int b = 0; b < BPB; ++b) {
        float a0 = 0.f, a1 = 0.f, a2 = 0.f;
        #pragma unroll
        for (int k = 0; k < Kn; ++k) {
            const int base = (b*Jn + jj[k]) * 6;
            uint2 q0 = *(const uint2*)&sm[base];
            uint2 q1 = *(const uint2*)&sm[base+2];
            uint2 q2 = *(const uint2*)&sm[base+4];
            float2 ma = unpackh2(q0.x), mb = unpackh2(q0.y);
            float2 mc = unpackh2(q1.x), md = unpackh2(q1.y);
            float2 me = unpackh2(q2.x), mf = unpackh2(q2.y);
            float wk = ww[k];
            a0 = fmaf(wk, fmaf(ma.x, vx, fmaf(ma.y, vy, fmaf(mb.x, vz, mb.y))), a0);
            a1 = fmaf(wk, fmaf(mc.x, vx, fmaf(mc.y, vy, fmaf(md.x, vz, md.y))), a1);
            a2 = fmaf(wk, fmaf(me.x, vx, fmaf(me.y, vy, fmaf(mf.x, vz, mf.y))), a2);
        }
        float* o = out + ((size_t)(b0 + b)*Vn + v) * 3;
        o[0] = a0; o[1] = a1; o[2] = a2;
    }
}

// ---------------------------------------------------------------------------
extern "C" void kernel_launch(void* const* d_in, const int* in_sizes, int n_in,
                              void* d_out, int out_size, void* d_ws, size_t ws_size,
                              hipStream_t stream)
{
    (void)in_sizes; (void)n_in; (void)out_size; (void)ws_size;

    const float* gp    = (const float*)d_in[0];   // global_pose   [8,6]
    const float* lp    = (const float*)d_in[1];   // local_pose    [8,960]
    const float* sc    = (const float*)d_in[2];   // scale         [8,161]
    const float* T     = (const float*)d_in[3];   // transform     [1127,1127]
    const float* toff  = (const float*)d_in[4];   // transform_offsets [1127]
    const float* joff  = (const float*)d_in[5];   // joint_offset  [161,3]
    const float* jrot  = (const float*)d_in[6];   // joint_rotation[161,4]
    const float* bind  = (const float*)d_in[7];   // bind_state    [1,161,8]
    const float* wts   = (const float*)d_in[8];   // skin_weights  [131072,8]
    const float* verts = (const float*)d_in[9];   // mesh_vertices [131072,3]
    const int*   idx   = (const int*)d_in[10];    // skin_indices  [131072,8]
    float* out = (float*)d_out;

    char* ws = (char*)d_ws;
    float*    params  = (float*)ws;                 // 8*1127 f32 @ 0     (36 KB)
    int*      parents = (int*)(ws + 40960);         // 161 ints   @ 40 KB
    unsigned* mat16   = (unsigned*)(ws + 45056);    // 7728 uints @ 44 KB (31 KB)

    k_front<<<Pn + NPARB, 256, 0, stream>>>(gp, lp, sc, T, toff, joff, jrot, bind, params, parents);
    k_fk   <<<(Bn*Jn + 63)/64, 64, 0, stream>>>(params, joff, jrot, bind, parents, mat16);
    k_skin <<<(Vn/256)*(Bn/BPB), 256, 0, stream>>>(mat16, wts, verts, idx, out);
}